// Round 8
// baseline (1125.619 us; speedup 1.0000x reference)
//
#include <hip/hip_runtime.h>
#include <hip/hip_fp16.h>

// GCN: 3x (h = X@W; agg = CSR-gather(norm_e * h[src]) + norm_self*h + b; relu)
// then mean-pool by graph id and a 128x8 linear head.
// R1: atomic scatter -> CSR gather (no f32 atomics in hot path).
// R2 (reverted): shfl-MLP gather regressed (not latency-bound).
// R3/R4: fp16 H16 payload. FETCH halved, time -20% only.
// R5 (reverted): src-bucketed rows -> null (FETCH/time unchanged).
// R6: gather is VMEM-instruction-throughput bound (51.2M loads ~ 3-4 cy/instr
//     through TA/L1 = observed 255 us). Halve instrs: 16 lanes/edge x 16 B
//     (float4 of 8 halves) instead of 32 lanes x 8 B. Packed int2 rec kept.
// R7: resubmit of R6 (container infra failure, no measurement).

#define THREADS 256

// ---------------- degree(int) / counts / dinv ----------------

__global__ __launch_bounds__(THREADS) void k_deg(const int* __restrict__ dst,
                                                 int* __restrict__ degi, int E) {
  int e = blockIdx.x * THREADS + threadIdx.x;
  if (e < E) atomicAdd(&degi[dst[e]], 1);
}

__global__ __launch_bounds__(THREADS) void k_cnt(const int* __restrict__ batch,
                                                 float* __restrict__ cnts, int N) {
  int i = blockIdx.x * THREADS + threadIdx.x;
  if (i < N) atomicAdd(&cnts[batch[i]], 1.0f);
}

__global__ __launch_bounds__(THREADS) void k_rsq(const int* __restrict__ degi,
                                                 float* __restrict__ dinv, int N) {
  int i = blockIdx.x * THREADS + threadIdx.x;
  if (i < N) dinv[i] = rsqrtf((float)degi[i] + 1.0f);
}

// ---------------- exclusive scan (3 kernels) ----------------

__global__ __launch_bounds__(THREADS) void k_scan1(const int* __restrict__ degi,
                                                   int* __restrict__ rowptr,
                                                   int* __restrict__ bsum, int N) {
  __shared__ int s[THREADS];
  int i = blockIdx.x * THREADS + threadIdx.x;
  int v = (i < N) ? degi[i] : 0;
  s[threadIdx.x] = v;
  __syncthreads();
#pragma unroll
  for (int off = 1; off < THREADS; off <<= 1) {
    int t = (threadIdx.x >= off) ? s[threadIdx.x - off] : 0;
    __syncthreads();
    s[threadIdx.x] += t;
    __syncthreads();
  }
  if (i < N) rowptr[i] = s[threadIdx.x] - v;  // exclusive
  if (threadIdx.x == THREADS - 1) bsum[blockIdx.x] = s[THREADS - 1];
}

__global__ __launch_bounds__(512) void k_scan2(int* __restrict__ bsum, int nb) {
  __shared__ int s[512];
  int v = (threadIdx.x < nb) ? bsum[threadIdx.x] : 0;
  s[threadIdx.x] = v;
  __syncthreads();
#pragma unroll
  for (int off = 1; off < 512; off <<= 1) {
    int t = (threadIdx.x >= off) ? s[threadIdx.x - off] : 0;
    __syncthreads();
    s[threadIdx.x] += t;
    __syncthreads();
  }
  if (threadIdx.x < nb) bsum[threadIdx.x] = s[threadIdx.x] - v;  // exclusive
}

__global__ __launch_bounds__(THREADS) void k_scan3(int* __restrict__ rowptr,
                                                   const int* __restrict__ bsum,
                                                   int N, int E) {
  int i = blockIdx.x * THREADS + threadIdx.x;
  if (i < N) rowptr[i] += bsum[blockIdx.x];
  if (i == 0) rowptr[N] = E;
}

// ---------------- CSR placement: packed {src, w} records by dst ----------------

__global__ __launch_bounds__(THREADS) void k_csr(const int* __restrict__ src,
                                                 const int* __restrict__ dst,
                                                 const int* __restrict__ rowptr,
                                                 int* __restrict__ cursor,
                                                 const float* __restrict__ dinv,
                                                 int2* __restrict__ rec, int E) {
  int e = blockIdx.x * THREADS + threadIdx.x;
  if (e >= E) return;
  int s = src[e];
  int d = dst[e];
  int pos = atomicAdd(&cursor[d], 1);
  int idx = rowptr[d] + pos;
  float w = dinv[s] * dinv[d];
  rec[idx] = make_int2(s, __float_as_int(w));
}

// ---------------- GEMM: H16[M,128] = fp16(X[M,128] @ W[128,128]) ----------------

__global__ __launch_bounds__(THREADS) void k_gemm128(const float* __restrict__ X,
                                                     const float* __restrict__ W,
                                                     __half* __restrict__ H16, int M) {
  __shared__ float4 sW[128 * 32];  // [k][colgroup] : W[k][c0..c0+3]
  const int t = threadIdx.x;
#pragma unroll
  for (int i = 0; i < 16; ++i) sW[t + i * 256] = ((const float4*)W)[t + i * 256];
  __syncthreads();

  const int tx = t & 31;
  const int ty = t >> 5;
  const int r0 = blockIdx.x * 64 + ty * 8;

  const float* xp[8];
#pragma unroll
  for (int i = 0; i < 8; ++i) {
    int r = r0 + i;
    if (r >= M) r = M - 1;
    xp[i] = X + (size_t)r * 128;
  }

  float4 acc[8];
#pragma unroll
  for (int i = 0; i < 8; ++i) acc[i] = make_float4(0.f, 0.f, 0.f, 0.f);

#pragma unroll 2
  for (int k = 0; k < 128; k += 4) {
    float4 xv[8];
#pragma unroll
    for (int i = 0; i < 8; ++i) xv[i] = *(const float4*)(xp[i] + k);
#pragma unroll
    for (int kk = 0; kk < 4; ++kk) {
      float4 w = sW[(k + kk) * 32 + tx];
#pragma unroll
      for (int i = 0; i < 8; ++i) {
        float xs = (kk == 0) ? xv[i].x : (kk == 1) ? xv[i].y : (kk == 2) ? xv[i].z : xv[i].w;
        acc[i].x = fmaf(xs, w.x, acc[i].x);
        acc[i].y = fmaf(xs, w.y, acc[i].y);
        acc[i].z = fmaf(xs, w.z, acc[i].z);
        acc[i].w = fmaf(xs, w.w, acc[i].w);
      }
    }
  }

#pragma unroll
  for (int i = 0; i < 8; ++i) {
    int r = r0 + i;
    if (r < M) {
      __half2 p[2];
      p[0] = __floats2half2_rn(acc[i].x, acc[i].y);
      p[1] = __floats2half2_rn(acc[i].z, acc[i].w);
      *(float2*)(H16 + (size_t)r * 128 + tx * 4) = *(float2*)p;
    }
  }
}

// ---------------- fp16 fragment load: 8 halves (16 B) -> 8 floats ----------------

struct f8 { float v[8]; };

__device__ inline f8 ld_h8(const __half* __restrict__ p) {
  float4 raw = *(const float4*)p;
  const __half2* h = (const __half2*)&raw;
  float2 a = __half22float2(h[0]);
  float2 b = __half22float2(h[1]);
  float2 c = __half22float2(h[2]);
  float2 d = __half22float2(h[3]);
  f8 o;
  o.v[0] = a.x; o.v[1] = a.y; o.v[2] = b.x; o.v[3] = b.y;
  o.v[4] = c.x; o.v[5] = c.y; o.v[6] = d.x; o.v[7] = d.y;
  return o;
}

// ---------------- gather: B[i] = sum_in w*H16[src] + dinv_i^2*H16[i] + bias ----------------
// 16 lanes per dst node, 16 B (8 halves) per lane: 17 VMEM instrs/edge-row
// group instead of 33 (VMEM-issue-throughput bound).

__global__ __launch_bounds__(THREADS) void k_gather(const __half* __restrict__ H16,
                                                    const int* __restrict__ rowptr,
                                                    const int2* __restrict__ rec,
                                                    const float* __restrict__ dinv,
                                                    const float* __restrict__ bias,
                                                    float* __restrict__ Bout, int N,
                                                    int relu,
                                                    const int* __restrict__ batch,
                                                    float* __restrict__ pooled) {
  int gid = blockIdx.x * THREADS + threadIdx.x;
  int i = gid >> 4;
  int lane = gid & 15;
  if (i >= N) return;
  int beg = rowptr[i];
  int end = rowptr[i + 1];
  const int co = lane * 8;  // this lane's 8-column slice

  float acc[8];
#pragma unroll
  for (int u = 0; u < 8; ++u) acc[u] = 0.f;

  int k = beg;
  for (; k + 3 < end; k += 4) {
    int2 r0 = rec[k],     r1 = rec[k + 1];
    int2 r2 = rec[k + 2], r3 = rec[k + 3];
    f8 h0 = ld_h8(H16 + (size_t)r0.x * 128 + co);
    f8 h1 = ld_h8(H16 + (size_t)r1.x * 128 + co);
    f8 h2 = ld_h8(H16 + (size_t)r2.x * 128 + co);
    f8 h3 = ld_h8(H16 + (size_t)r3.x * 128 + co);
    float w0 = __int_as_float(r0.y), w1 = __int_as_float(r1.y);
    float w2 = __int_as_float(r2.y), w3 = __int_as_float(r3.y);
#pragma unroll
    for (int u = 0; u < 8; ++u) {
      acc[u] = fmaf(w0, h0.v[u], acc[u]);
      acc[u] = fmaf(w1, h1.v[u], acc[u]);
      acc[u] = fmaf(w2, h2.v[u], acc[u]);
      acc[u] = fmaf(w3, h3.v[u], acc[u]);
    }
  }
  for (; k < end; ++k) {
    int2 r0 = rec[k];
    float w0 = __int_as_float(r0.y);
    f8 h0 = ld_h8(H16 + (size_t)r0.x * 128 + co);
#pragma unroll
    for (int u = 0; u < 8; ++u) acc[u] = fmaf(w0, h0.v[u], acc[u]);
  }

  float di = dinv[i];
  float ns = di * di;
  f8 hs = ld_h8(H16 + (size_t)i * 128 + co);
  float4 bb0 = *(const float4*)(bias + co);
  float4 bb1 = *(const float4*)(bias + co + 4);
  float v[8];
  v[0] = fmaf(hs.v[0], ns, acc[0]) + bb0.x;
  v[1] = fmaf(hs.v[1], ns, acc[1]) + bb0.y;
  v[2] = fmaf(hs.v[2], ns, acc[2]) + bb0.z;
  v[3] = fmaf(hs.v[3], ns, acc[3]) + bb0.w;
  v[4] = fmaf(hs.v[4], ns, acc[4]) + bb1.x;
  v[5] = fmaf(hs.v[5], ns, acc[5]) + bb1.y;
  v[6] = fmaf(hs.v[6], ns, acc[6]) + bb1.z;
  v[7] = fmaf(hs.v[7], ns, acc[7]) + bb1.w;
  if (relu) {
#pragma unroll
    for (int u = 0; u < 8; ++u) v[u] = fmaxf(v[u], 0.f);
  }
  *(float4*)(Bout + (size_t)i * 128 + co)     = make_float4(v[0], v[1], v[2], v[3]);
  *(float4*)(Bout + (size_t)i * 128 + co + 4) = make_float4(v[4], v[5], v[6], v[7]);

  if (pooled) {
    int g = batch[i];
    float* o = pooled + (size_t)g * 128 + co;
#pragma unroll
    for (int u = 0; u < 8; ++u) atomicAdd(o + u, v[u]);
  }
}

// ---------------- head ----------------

__global__ __launch_bounds__(THREADS) void k_head(const float* __restrict__ pooled,
                                                  const float* __restrict__ cnts,
                                                  const float* __restrict__ Wl,
                                                  const float* __restrict__ bl,
                                                  float* __restrict__ out, int G) {
  int gid = blockIdx.x * THREADS + threadIdx.x;
  int g = gid >> 3;
  int o = gid & 7;
  if (g >= G) return;
  float acc = 0.f;
#pragma unroll 8
  for (int k = 0; k < 128; ++k) acc = fmaf(pooled[(size_t)g * 128 + k], Wl[k * 8 + o], acc);
  out[g * 8 + o] = acc / fmaxf(cnts[g], 1.0f) + bl[o];
}

// ---------------- launch ----------------

extern "C" void kernel_launch(void* const* d_in, const int* in_sizes, int n_in,
                              void* d_out, int out_size, void* d_ws, size_t ws_size,
                              hipStream_t stream) {
  const float* x     = (const float*)d_in[0];
  const int*   ei    = (const int*)d_in[1];
  const int*   batch = (const int*)d_in[3];
  const float* W1 = (const float*)d_in[4];
  const float* b1 = (const float*)d_in[5];
  const float* W2 = (const float*)d_in[6];
  const float* b2 = (const float*)d_in[7];
  const float* W3 = (const float*)d_in[8];
  const float* b3 = (const float*)d_in[9];
  const float* Wl = (const float*)d_in[10];
  const float* bl = (const float*)d_in[11];
  float* out = (float*)d_out;

  const int N = in_sizes[0] / 128;
  const int E = in_sizes[1] / 2;
  const int G = out_size / 8;
  const int* srcp = ei;
  const int* dstp = ei + E;

  char* ws = (char*)d_ws;
  __half* H16 = (__half*)ws;                       // [N,128] fp16 GEMM output
  float*  B   = (float*)(H16 + (size_t)N * 128);   // [N,128] fp32 agg/activation
  // zeroed region: degi, cursor, cnts, pooled (contiguous)
  int*   degi   = (int*)(B + (size_t)N * 128);     // N
  int*   cursor = degi + N;                        // N
  float* cnts   = (float*)(cursor + N);            // G
  float* pooled = cnts + G;                        // G*128
  // non-zeroed scratch
  float* dinv    = pooled + (size_t)G * 128;       // N
  int*   rowptr  = (int*)(dinv + N);               // N+1
  int*   bsum    = rowptr + N + 1;                 // scan partials (<=2048)
  int2*  rec     = (int2*)(bsum + 2048);           // E packed records

  const size_t zero_bytes = ((size_t)2 * N + G + (size_t)G * 128) * sizeof(float);
  hipMemsetAsync(degi, 0, zero_bytes, stream);

  const int nbE = (E + THREADS - 1) / THREADS;
  const int nbN = (N + THREADS - 1) / THREADS;

  // ---- CSR build (once per call, reused by all 3 layers) ----
  k_deg<<<nbE, THREADS, 0, stream>>>(dstp, degi, E);
  k_cnt<<<nbN, THREADS, 0, stream>>>(batch, cnts, N);
  k_rsq<<<nbN, THREADS, 0, stream>>>(degi, dinv, N);
  k_scan1<<<nbN, THREADS, 0, stream>>>(degi, rowptr, bsum, N);
  k_scan2<<<1, 512, 0, stream>>>(bsum, nbN);
  k_scan3<<<nbN, THREADS, 0, stream>>>(rowptr, bsum, N, E);
  k_csr<<<nbE, THREADS, 0, stream>>>(srcp, dstp, rowptr, cursor, dinv, rec, E);

  const int gemm_blocks = (N + 63) / 64;
  const int gat_blocks = (int)(((long long)N * 16 + THREADS - 1) / THREADS);

  // ---- layer 1 ----
  k_gemm128<<<gemm_blocks, THREADS, 0, stream>>>(x, W1, H16, N);
  k_gather<<<gat_blocks, THREADS, 0, stream>>>(H16, rowptr, rec, dinv, b1, B, N, 1,
                                               nullptr, nullptr);
  // ---- layer 2 ----
  k_gemm128<<<gemm_blocks, THREADS, 0, stream>>>(B, W2, H16, N);
  k_gather<<<gat_blocks, THREADS, 0, stream>>>(H16, rowptr, rec, dinv, b2, B, N, 1,
                                               nullptr, nullptr);
  // ---- layer 3 (no relu, fused mean-pool accumulation) ----
  k_gemm128<<<gemm_blocks, THREADS, 0, stream>>>(B, W3, H16, N);
  k_gather<<<gat_blocks, THREADS, 0, stream>>>(H16, rowptr, rec, dinv, b3, B, N, 0,
                                               batch, pooled);

  // ---- head ----
  k_head<<<(G * 8 + THREADS - 1) / THREADS, THREADS, 0, stream>>>(pooled, cnts, Wl, bl, out, G);
}

// Round 9
// 817.299 us; speedup vs baseline: 1.3772x; 1.3772x over previous
//
#include <hip/hip_runtime.h>
#include <hip/hip_fp16.h>

// GCN: 3x (h = X@W; agg = CSR-gather(norm_e * h[src]) + norm_self*h + b; relu)
// then mean-pool by graph id and a 128x8 linear head.
// R1: atomic scatter -> CSR gather. R2 (reverted): shfl-MLP. R3: fp16 H16.
// R5 (reverted): src-bucketing null -> FETCH is at coupon-collector floor.
// R6 (reverted): 16-lane x 16B gather 2x WORSE; also write-amp 250->450 MB.
//     Conclusion: gather = random-granule path ~1.7-2 TB/s; fetch at floor;
//     write side is the reducible term (250 MB vs 51.2 MB of data).
// R8: R3 shape (32 lanes x 8B, unroll 4) + int2 rec; B stored as fp16 and
//     GEMM reads fp16; non-temporal stores for B16/H16 (streaming, never
//     re-read by producer) to cut write-allocate/L2 pollution.

#define THREADS 256

// ---------------- degree(int) / counts / dinv ----------------

__global__ __launch_bounds__(THREADS) void k_deg(const int* __restrict__ dst,
                                                 int* __restrict__ degi, int E) {
  int e = blockIdx.x * THREADS + threadIdx.x;
  if (e < E) atomicAdd(&degi[dst[e]], 1);
}

__global__ __launch_bounds__(THREADS) void k_cnt(const int* __restrict__ batch,
                                                 float* __restrict__ cnts, int N) {
  int i = blockIdx.x * THREADS + threadIdx.x;
  if (i < N) atomicAdd(&cnts[batch[i]], 1.0f);
}

__global__ __launch_bounds__(THREADS) void k_rsq(const int* __restrict__ degi,
                                                 float* __restrict__ dinv, int N) {
  int i = blockIdx.x * THREADS + threadIdx.x;
  if (i < N) dinv[i] = rsqrtf((float)degi[i] + 1.0f);
}

// ---------------- exclusive scan (3 kernels) ----------------

__global__ __launch_bounds__(THREADS) void k_scan1(const int* __restrict__ degi,
                                                   int* __restrict__ rowptr,
                                                   int* __restrict__ bsum, int N) {
  __shared__ int s[THREADS];
  int i = blockIdx.x * THREADS + threadIdx.x;
  int v = (i < N) ? degi[i] : 0;
  s[threadIdx.x] = v;
  __syncthreads();
#pragma unroll
  for (int off = 1; off < THREADS; off <<= 1) {
    int t = (threadIdx.x >= off) ? s[threadIdx.x - off] : 0;
    __syncthreads();
    s[threadIdx.x] += t;
    __syncthreads();
  }
  if (i < N) rowptr[i] = s[threadIdx.x] - v;  // exclusive
  if (threadIdx.x == THREADS - 1) bsum[blockIdx.x] = s[THREADS - 1];
}

__global__ __launch_bounds__(512) void k_scan2(int* __restrict__ bsum, int nb) {
  __shared__ int s[512];
  int v = (threadIdx.x < nb) ? bsum[threadIdx.x] : 0;
  s[threadIdx.x] = v;
  __syncthreads();
#pragma unroll
  for (int off = 1; off < 512; off <<= 1) {
    int t = (threadIdx.x >= off) ? s[threadIdx.x - off] : 0;
    __syncthreads();
    s[threadIdx.x] += t;
    __syncthreads();
  }
  if (threadIdx.x < nb) bsum[threadIdx.x] = s[threadIdx.x] - v;  // exclusive
}

__global__ __launch_bounds__(THREADS) void k_scan3(int* __restrict__ rowptr,
                                                   const int* __restrict__ bsum,
                                                   int N, int E) {
  int i = blockIdx.x * THREADS + threadIdx.x;
  if (i < N) rowptr[i] += bsum[blockIdx.x];
  if (i == 0) rowptr[N] = E;
}

// ---------------- CSR placement: packed {src, w} records by dst ----------------

__global__ __launch_bounds__(THREADS) void k_csr(const int* __restrict__ src,
                                                 const int* __restrict__ dst,
                                                 const int* __restrict__ rowptr,
                                                 int* __restrict__ cursor,
                                                 const float* __restrict__ dinv,
                                                 int2* __restrict__ rec, int E) {
  int e = blockIdx.x * THREADS + threadIdx.x;
  if (e >= E) return;
  int s = src[e];
  int d = dst[e];
  int pos = atomicAdd(&cursor[d], 1);
  int idx = rowptr[d] + pos;
  float w = dinv[s] * dinv[d];
  rec[idx] = make_int2(s, __float_as_int(w));
}

// ---------------- row-fragment loaders: 4 elems -> float4 ----------------

__device__ inline float4 ldrow4(const float* __restrict__ p) {
  return *(const float4*)p;
}

__device__ inline float4 ldrow4(const __half* __restrict__ p) {
  float2 raw = *(const float2*)p;  // 4 halves
  const __half2* h = (const __half2*)&raw;
  float2 a = __half22float2(h[0]);
  float2 b = __half22float2(h[1]);
  return make_float4(a.x, a.y, b.x, b.y);
}

// fp16 pack + non-temporal 8 B store
__device__ inline void st_nt_h4(__half* __restrict__ p, float x, float y,
                                float z, float w) {
  union {
    __half2 h2[2];
    unsigned long long u;
  } cv;
  cv.h2[0] = __floats2half2_rn(x, y);
  cv.h2[1] = __floats2half2_rn(z, w);
  __builtin_nontemporal_store(cv.u, (unsigned long long*)p);
}

// ---------------- GEMM: H16[M,128] = fp16(X[M,128] @ W[128,128]) ----------------

template <typename T>
__global__ __launch_bounds__(THREADS) void k_gemm128(const T* __restrict__ X,
                                                     const float* __restrict__ W,
                                                     __half* __restrict__ H16, int M) {
  __shared__ float4 sW[128 * 32];  // [k][colgroup] : W[k][c0..c0+3]
  const int t = threadIdx.x;
#pragma unroll
  for (int i = 0; i < 16; ++i) sW[t + i * 256] = ((const float4*)W)[t + i * 256];
  __syncthreads();

  const int tx = t & 31;
  const int ty = t >> 5;
  const int r0 = blockIdx.x * 64 + ty * 8;

  const T* xp[8];
#pragma unroll
  for (int i = 0; i < 8; ++i) {
    int r = r0 + i;
    if (r >= M) r = M - 1;
    xp[i] = X + (size_t)r * 128;
  }

  float4 acc[8];
#pragma unroll
  for (int i = 0; i < 8; ++i) acc[i] = make_float4(0.f, 0.f, 0.f, 0.f);

#pragma unroll 2
  for (int k = 0; k < 128; k += 4) {
    float4 xv[8];
#pragma unroll
    for (int i = 0; i < 8; ++i) xv[i] = ldrow4(xp[i] + k);
#pragma unroll
    for (int kk = 0; kk < 4; ++kk) {
      float4 w = sW[(k + kk) * 32 + tx];
#pragma unroll
      for (int i = 0; i < 8; ++i) {
        float xs = (kk == 0) ? xv[i].x : (kk == 1) ? xv[i].y : (kk == 2) ? xv[i].z : xv[i].w;
        acc[i].x = fmaf(xs, w.x, acc[i].x);
        acc[i].y = fmaf(xs, w.y, acc[i].y);
        acc[i].z = fmaf(xs, w.z, acc[i].z);
        acc[i].w = fmaf(xs, w.w, acc[i].w);
      }
    }
  }

#pragma unroll
  for (int i = 0; i < 8; ++i) {
    int r = r0 + i;
    if (r < M)
      st_nt_h4(H16 + (size_t)r * 128 + tx * 4, acc[i].x, acc[i].y, acc[i].z, acc[i].w);
  }
}

// ---------------- gather: B16[i] = fp16(sum_in w*H16[src] + dinv_i^2*H16[i] + bias) ----------------
// 32 lanes per dst node, 8 B (4 halves) per lane; unroll 4. NT store of B16.

__global__ __launch_bounds__(THREADS) void k_gather(const __half* __restrict__ H16,
                                                    const int* __restrict__ rowptr,
                                                    const int2* __restrict__ rec,
                                                    const float* __restrict__ dinv,
                                                    const float* __restrict__ bias,
                                                    __half* __restrict__ B16, int N,
                                                    int relu,
                                                    const int* __restrict__ batch,
                                                    float* __restrict__ pooled) {
  int gid = blockIdx.x * THREADS + threadIdx.x;
  int i = gid >> 5;
  int lane = gid & 31;
  if (i >= N) return;
  int beg = rowptr[i];
  int end = rowptr[i + 1];

  float4 acc = make_float4(0.f, 0.f, 0.f, 0.f);
  int k = beg;
  for (; k + 3 < end; k += 4) {
    int2 r0 = rec[k],     r1 = rec[k + 1];
    int2 r2 = rec[k + 2], r3 = rec[k + 3];
    float4 h0 = ldrow4(H16 + (size_t)r0.x * 128 + lane * 4);
    float4 h1 = ldrow4(H16 + (size_t)r1.x * 128 + lane * 4);
    float4 h2 = ldrow4(H16 + (size_t)r2.x * 128 + lane * 4);
    float4 h3 = ldrow4(H16 + (size_t)r3.x * 128 + lane * 4);
    float w0 = __int_as_float(r0.y), w1 = __int_as_float(r1.y);
    float w2 = __int_as_float(r2.y), w3 = __int_as_float(r3.y);
    acc.x = fmaf(w0, h0.x, acc.x); acc.y = fmaf(w0, h0.y, acc.y);
    acc.z = fmaf(w0, h0.z, acc.z); acc.w = fmaf(w0, h0.w, acc.w);
    acc.x = fmaf(w1, h1.x, acc.x); acc.y = fmaf(w1, h1.y, acc.y);
    acc.z = fmaf(w1, h1.z, acc.z); acc.w = fmaf(w1, h1.w, acc.w);
    acc.x = fmaf(w2, h2.x, acc.x); acc.y = fmaf(w2, h2.y, acc.y);
    acc.z = fmaf(w2, h2.z, acc.z); acc.w = fmaf(w2, h2.w, acc.w);
    acc.x = fmaf(w3, h3.x, acc.x); acc.y = fmaf(w3, h3.y, acc.y);
    acc.z = fmaf(w3, h3.z, acc.z); acc.w = fmaf(w3, h3.w, acc.w);
  }
  for (; k < end; ++k) {
    int2 r0 = rec[k];
    float w0 = __int_as_float(r0.y);
    float4 h0 = ldrow4(H16 + (size_t)r0.x * 128 + lane * 4);
    acc.x = fmaf(w0, h0.x, acc.x); acc.y = fmaf(w0, h0.y, acc.y);
    acc.z = fmaf(w0, h0.z, acc.z); acc.w = fmaf(w0, h0.w, acc.w);
  }

  float di = dinv[i];
  float ns = di * di;
  float4 hs = ldrow4(H16 + (size_t)i * 128 + lane * 4);
  float4 bb = *(const float4*)(bias + lane * 4);
  float4 v;
  v.x = fmaf(hs.x, ns, acc.x) + bb.x;
  v.y = fmaf(hs.y, ns, acc.y) + bb.y;
  v.z = fmaf(hs.z, ns, acc.z) + bb.z;
  v.w = fmaf(hs.w, ns, acc.w) + bb.w;
  if (relu) {
    v.x = fmaxf(v.x, 0.f);
    v.y = fmaxf(v.y, 0.f);
    v.z = fmaxf(v.z, 0.f);
    v.w = fmaxf(v.w, 0.f);
  }
  st_nt_h4(B16 + (size_t)i * 128 + lane * 4, v.x, v.y, v.z, v.w);

  if (pooled) {
    int g = batch[i];
    float* o = pooled + (size_t)g * 128 + lane * 4;
    atomicAdd(o + 0, v.x);
    atomicAdd(o + 1, v.y);
    atomicAdd(o + 2, v.z);
    atomicAdd(o + 3, v.w);
  }
}

// ---------------- head ----------------

__global__ __launch_bounds__(THREADS) void k_head(const float* __restrict__ pooled,
                                                  const float* __restrict__ cnts,
                                                  const float* __restrict__ Wl,
                                                  const float* __restrict__ bl,
                                                  float* __restrict__ out, int G) {
  int gid = blockIdx.x * THREADS + threadIdx.x;
  int g = gid >> 3;
  int o = gid & 7;
  if (g >= G) return;
  float acc = 0.f;
#pragma unroll 8
  for (int k = 0; k < 128; ++k) acc = fmaf(pooled[(size_t)g * 128 + k], Wl[k * 8 + o], acc);
  out[g * 8 + o] = acc / fmaxf(cnts[g], 1.0f) + bl[o];
}

// ---------------- launch ----------------

extern "C" void kernel_launch(void* const* d_in, const int* in_sizes, int n_in,
                              void* d_out, int out_size, void* d_ws, size_t ws_size,
                              hipStream_t stream) {
  const float* x     = (const float*)d_in[0];
  const int*   ei    = (const int*)d_in[1];
  const int*   batch = (const int*)d_in[3];
  const float* W1 = (const float*)d_in[4];
  const float* b1 = (const float*)d_in[5];
  const float* W2 = (const float*)d_in[6];
  const float* b2 = (const float*)d_in[7];
  const float* W3 = (const float*)d_in[8];
  const float* b3 = (const float*)d_in[9];
  const float* Wl = (const float*)d_in[10];
  const float* bl = (const float*)d_in[11];
  float* out = (float*)d_out;

  const int N = in_sizes[0] / 128;
  const int E = in_sizes[1] / 2;
  const int G = out_size / 8;
  const int* srcp = ei;
  const int* dstp = ei + E;

  char* ws = (char*)d_ws;
  __half* H16 = (__half*)ws;                       // [N,128] fp16 GEMM output
  __half* B16 = H16 + (size_t)N * 128;             // [N,128] fp16 activations
  // zeroed region: degi, cursor, cnts, pooled (contiguous)
  int*   degi   = (int*)(B16 + (size_t)N * 128);   // N
  int*   cursor = degi + N;                        // N
  float* cnts   = (float*)(cursor + N);            // G
  float* pooled = cnts + G;                        // G*128
  // non-zeroed scratch
  float* dinv    = pooled + (size_t)G * 128;       // N
  int*   rowptr  = (int*)(dinv + N);               // N+1
  int*   bsum    = rowptr + N + 1;                 // scan partials (<=2048)
  int2*  rec     = (int2*)(bsum + 2048);           // E packed records

  const size_t zero_bytes = ((size_t)2 * N + G + (size_t)G * 128) * sizeof(float);
  hipMemsetAsync(degi, 0, zero_bytes, stream);

  const int nbE = (E + THREADS - 1) / THREADS;
  const int nbN = (N + THREADS - 1) / THREADS;

  // ---- CSR build (once per call, reused by all 3 layers) ----
  k_deg<<<nbE, THREADS, 0, stream>>>(dstp, degi, E);
  k_cnt<<<nbN, THREADS, 0, stream>>>(batch, cnts, N);
  k_rsq<<<nbN, THREADS, 0, stream>>>(degi, dinv, N);
  k_scan1<<<nbN, THREADS, 0, stream>>>(degi, rowptr, bsum, N);
  k_scan2<<<1, 512, 0, stream>>>(bsum, nbN);
  k_scan3<<<nbN, THREADS, 0, stream>>>(rowptr, bsum, N, E);
  k_csr<<<nbE, THREADS, 0, stream>>>(srcp, dstp, rowptr, cursor, dinv, rec, E);

  const int gemm_blocks = (N + 63) / 64;
  const int gat_blocks = (int)(((long long)N * 32 + THREADS - 1) / THREADS);

  // ---- layer 1 ----
  k_gemm128<float><<<gemm_blocks, THREADS, 0, stream>>>(x, W1, H16, N);
  k_gather<<<gat_blocks, THREADS, 0, stream>>>(H16, rowptr, rec, dinv, b1, B16, N, 1,
                                               nullptr, nullptr);
  // ---- layer 2 ----
  k_gemm128<__half><<<gemm_blocks, THREADS, 0, stream>>>(B16, W2, H16, N);
  k_gather<<<gat_blocks, THREADS, 0, stream>>>(H16, rowptr, rec, dinv, b2, B16, N, 1,
                                               nullptr, nullptr);
  // ---- layer 3 (no relu, fused mean-pool accumulation) ----
  k_gemm128<__half><<<gemm_blocks, THREADS, 0, stream>>>(B16, W3, H16, N);
  k_gather<<<gat_blocks, THREADS, 0, stream>>>(H16, rowptr, rec, dinv, b3, B16, N, 0,
                                               batch, pooled);

  // ---- head ----
  k_head<<<(G * 8 + THREADS - 1) / THREADS, THREADS, 0, stream>>>(pooled, cnts, Wl, bl, out, G);
}